// Round 2
// baseline (539.983 us; speedup 1.0000x reference)
//
#include <hip/hip_runtime.h>
#include <hip/hip_bf16.h>

// Problem constants (B=4, L=2048, D=512, M=1200, H=6)
// KEY INSIGHT: keyval is broadcast over L -> K rows identical -> softmax == 1/L exactly,
// mha == V[b] (per-batch constant), and leaky(slope=1) is identity so W2a@W2b folds.
// R10 = best of R8+R9: 5 dispatches, no memset, no atomics.
//   k1: A1 cast, W2b transpose, V direct-GEMV, fill F1
//   k3: Wfold = A1@W2bT non-split-K MFMA -> bf16 WfT (transposed epilogue) + fp32 folded
//       bias row fb = bfold + b2b; oc = V@Wff+bff direct; fill F3
//   k4: ln1 -> X bf16; fill F4
//   k5: out2 = X @ Wfold via 64x64 MFMA tiles (1024 blocks, 8KB+8KB LDS); fill F5
//   k6: ln2 + kv -> out3; fill F6
// (R9's 16x512 fused k56 regressed: 64KB B-panel/block -> 2 blocks/CU and 4x WfT
//  re-staging traffic; reverted to R8's k5/k6 split.)

typedef __bf16 bf16x8 __attribute__((ext_vector_type(8)));
typedef float f32x4 __attribute__((ext_vector_type(4)));

constexpr size_t OUT3_N = 4ull * 2048 * 512;            // 4,194,304
constexpr size_t SM_N4  = (4ull * 6 * 2048 * 2048) / 4; // 25,165,824 f32x4
constexpr float  SMV    = 1.0f / 2048.0f;

// fill slice schedule (f32x4 units) — disjoint, covers SM exactly (R8-balanced)
constexpr size_t S1 = 0,        C1 = 5375000;
constexpr size_t S3 = 5375000,  C3 = 5687500;
constexpr size_t S4 = 11062500, C4 = 4750000;
constexpr size_t S5 = 15812500, C5 = 5187500;
constexpr size_t S6 = 21000000, C6 = 4165824;
static_assert(S6 + C6 == SM_N4, "fill slices must cover sm");

__device__ __forceinline__ void fill_slice(f32x4* __restrict__ p, size_t base, size_t cnt,
                                           int fb, int nfb){
    const f32x4 v = { SMV, SMV, SMV, SMV };
    const size_t stride = (size_t)nfb * 256;
    for (size_t j = (size_t)fb * 256 + threadIdx.x; j < cnt; j += stride)
        __builtin_nontemporal_store(v, p + base + j);
}

// ---------------- shared 64x64 MFMA tile core (BK=64, 4 waves 2x2, swizzled LDS) ----
// computes acc[2][2] for C[64x64 at bm,bn] = A[.,Kdim] @ BT[.,Kdim]^T over full K
template<int KDIM>
__device__ __forceinline__ void gemm_core(const __bf16* __restrict__ A,
        const __bf16* __restrict__ BT, int bm, int bn,
        __bf16* As, __bf16* Bs, f32x4 (&acc)[2][2]){
    const int tid = threadIdx.x, wave = tid >> 6, lane = tid & 63;
    const int r_st = wave * 8 + (lane >> 3);
    const int c8g  = (lane & 7) ^ (r_st & 7);
    const __bf16* Ag = A  + (size_t)(bm + r_st) * KDIM + c8g * 8;
    const __bf16* Bg = BT + (size_t)(bn + r_st) * KDIM + c8g * 8;
    const size_t rowskip = (size_t)32 * KDIM;
    const int wm = (wave >> 1) * 32, wn = (wave & 1) * 32;
    const int lm = lane & 15, lq = lane >> 4;
    for (int k0 = 0; k0 < KDIM; k0 += 64){
        __builtin_amdgcn_global_load_lds(
            (const __attribute__((address_space(1))) void*)(Ag + k0),
            (__attribute__((address_space(3))) void*)&As[wave * 512], 16, 0, 0);
        __builtin_amdgcn_global_load_lds(
            (const __attribute__((address_space(1))) void*)(Ag + k0 + rowskip),
            (__attribute__((address_space(3))) void*)&As[2048 + wave * 512], 16, 0, 0);
        __builtin_amdgcn_global_load_lds(
            (const __attribute__((address_space(1))) void*)(Bg + k0),
            (__attribute__((address_space(3))) void*)&Bs[wave * 512], 16, 0, 0);
        __builtin_amdgcn_global_load_lds(
            (const __attribute__((address_space(1))) void*)(Bg + k0 + rowskip),
            (__attribute__((address_space(3))) void*)&Bs[2048 + wave * 512], 16, 0, 0);
        __syncthreads();
        #pragma unroll
        for (int kb = 0; kb < 64; kb += 32){
            const int sw = (((kb >> 3) + lq) ^ (lm & 7)) << 3;
            bf16x8 a0 = *(const bf16x8*)&As[(wm + lm) * 64 + sw];
            bf16x8 a1 = *(const bf16x8*)&As[(wm + 16 + lm) * 64 + sw];
            bf16x8 b0 = *(const bf16x8*)&Bs[(wn + lm) * 64 + sw];
            bf16x8 b1 = *(const bf16x8*)&Bs[(wn + 16 + lm) * 64 + sw];
            acc[0][0] = __builtin_amdgcn_mfma_f32_16x16x32_bf16(a0, b0, acc[0][0], 0, 0, 0);
            acc[0][1] = __builtin_amdgcn_mfma_f32_16x16x32_bf16(a0, b1, acc[0][1], 0, 0, 0);
            acc[1][0] = __builtin_amdgcn_mfma_f32_16x16x32_bf16(a1, b0, acc[1][0], 0, 0, 0);
            acc[1][1] = __builtin_amdgcn_mfma_f32_16x16x32_bf16(a1, b1, acc[1][1], 0, 0, 0);
        }
        __syncthreads();
    }
}

// ---------------- k1: A1 cast, W2b transpose, V direct-GEMV; fill F1 ----------------
__global__ __launch_bounds__(256) void k1_prep(const float* __restrict__ W2a,
        const float* __restrict__ b2a, __bf16* __restrict__ A1,
        const float* __restrict__ W2b, __bf16* __restrict__ W2bT,
        const float* __restrict__ keyval, const float* __restrict__ Wkv,
        const float* __restrict__ bkv, float* __restrict__ V, f32x4* __restrict__ smf){
    __shared__ float sh[32 * 33];
    const int bid = blockIdx.x, tid = threadIdx.x;
    if (bid < 1152){
        int r = bid >> 1;
        int c = (bid & 1) * 1024 + tid * 4;
        float4 v;
        if (r < 512)       v = *(const float4*)(W2a + (size_t)r * 2048 + c);
        else if (r == 512) v = *(const float4*)(b2a + c);
        else               v = make_float4(0.f, 0.f, 0.f, 0.f);
        __bf16* o = A1 + (size_t)r * 2048 + c;
        o[0] = (__bf16)v.x; o[1] = (__bf16)v.y; o[2] = (__bf16)v.z; o[3] = (__bf16)v.w;
    } else if (bid < 2176){
        int t = bid - 1152;                    // 1024 tiles over W2b [2048][512]
        int c0 = (t & 15) * 32, r0 = (t >> 4) * 32;
        int tx = tid & 31, ty = tid >> 5;
        for (int i = ty; i < 32; i += 8)
            sh[i * 33 + tx] = W2b[(size_t)(r0 + i) * 512 + c0 + tx];
        __syncthreads();
        for (int i = ty; i < 32; i += 8)
            W2bT[(size_t)(c0 + i) * 2048 + r0 + tx] = (__bf16)sh[tx * 33 + i];
    } else if (bid < 2196){
        int i = bid - 2176;                    // 20: b(4) x mc(5), no atomics
        int b = i & 3, mc = i >> 2;
        int m = mc * 240 + tid;
        if (tid < 240){
            float acc = bkv[1200 + m];
            const float* kvb = keyval + (size_t)b * 512;
            #pragma unroll 8
            for (int d = 0; d < 512; ++d)
                acc += kvb[d] * Wkv[(size_t)d * 2400 + 1200 + m];
            V[b * 1200 + m] = acc;
        }
    }
    fill_slice(smf, S1, C1, bid, 2848);
}

// ---------------- k3: Wfold GEMM -> WfT bf16 + fb; oc direct-GEMV; fill F3 ----------------
__global__ __launch_bounds__(256) void k3_wf_oc(const __bf16* __restrict__ A1,
        const __bf16* __restrict__ W2bT, __bf16* __restrict__ WfT,
        float* __restrict__ fb, const float* __restrict__ b2b,
        const float* __restrict__ V, const float* __restrict__ Wff,
        const float* __restrict__ bff, float* __restrict__ oc, f32x4* __restrict__ smf){
    const int bid = blockIdx.x, t = threadIdx.x;
    if (bid < 72){                             // 9 row-tiles x 8 col-tiles, K=2048 full
        __shared__ __bf16 As[64 * 64];
        __shared__ __bf16 Bs[64 * 64];
        const int bm = (bid % 9) * 64, bn = (bid / 9) * 64;
        f32x4 acc[2][2] = {};
        gemm_core<2048>(A1, W2bT, bm, bn, As, Bs, acc);
        const int lane = t & 63, wave = t >> 6;
        const int wm = (wave >> 1) * 32, wn = (wave & 1) * 32;
        const int lm = lane & 15, lq = lane >> 4;
        #pragma unroll
        for (int mi = 0; mi < 2; ++mi)
          #pragma unroll
          for (int ni = 0; ni < 2; ++ni)
            #pragma unroll
            for (int r = 0; r < 4; ++r){
                int row = bm + wm + mi * 16 + lq * 4 + r;   // C/D: row=(lane>>4)*4+reg
                int col = bn + wn + ni * 16 + lm;           //      col=lane&15
                if (row < 512)       WfT[(size_t)col * 512 + row] = (__bf16)acc[mi][ni][r];
                else if (row == 512) fb[col] = acc[mi][ni][r] + b2b[col];
            }
    } else if (bid < 104){                     // oc: b(4) x jc(8), 4-wave K-split in-block
        __shared__ float sh[4 * 64];
        int i = bid - 72;
        int b = i & 3, jc = i >> 2;
        int wv = t >> 6, j = jc * 64 + (t & 63);
        const float* vb = V + b * 1200;
        float acc = 0.f;
        int m0 = wv * 300;
        #pragma unroll 4
        for (int m = m0; m < m0 + 300; ++m)
            acc += vb[m] * Wff[(size_t)m * 512 + j];
        sh[t] = acc;
        __syncthreads();
        if (t < 64)
            oc[b * 512 + jc * 64 + t] = sh[t] + sh[64 + t] + sh[128 + t] + sh[192 + t]
                                      + bff[jc * 64 + t];
    }
    fill_slice(smf, S3, C3, bid, 2048);
}

// ---------------- k4: ln1 -> X bf16; fill F4 ----------------
__global__ __launch_bounds__(256) void k4_ln1(const float* __restrict__ q,
        const float* __restrict__ oc, const float* __restrict__ g1,
        const float* __restrict__ b1, __bf16* __restrict__ Xb, f32x4* __restrict__ smf){
    __shared__ float sh[8];
    const int bid = blockIdx.x, t = threadIdx.x;
    if (bid < 8192){
        const int b = bid >> 11;
        const size_t base = (size_t)bid * 512;
        float2 qv = *(const float2*)(q + base + 2 * t);
        float2 ov = *(const float2*)(oc + (size_t)b * 512 + 2 * t);
        float v0 = qv.x + ov.x, v1 = qv.y + ov.y;
        float s = v0 + v1, ss = v0 * v0 + v1 * v1;
        for (int off = 32; off; off >>= 1){ s += __shfl_down(s, off); ss += __shfl_down(ss, off); }
        int wv = t >> 6, ln = t & 63;
        if (ln == 0){ sh[wv] = s; sh[4 + wv] = ss; }
        __syncthreads();
        if (t == 0){
            float S  = sh[0] + sh[1] + sh[2] + sh[3];
            float SS = sh[4] + sh[5] + sh[6] + sh[7];
            float m = S * (1.0f / 512.0f);
            float var = SS * (1.0f / 512.0f) - m * m;
            sh[0] = m; sh[1] = rsqrtf(var + 1e-5f);
        }
        __syncthreads();
        float m = sh[0], r = sh[1];
        float2 gv = *(const float2*)(g1 + 2 * t);
        float2 bv = *(const float2*)(b1 + 2 * t);
        union { __bf16 h[2]; unsigned u; } pk;
        pk.h[0] = (__bf16)((v0 - m) * r * gv.x + bv.x);
        pk.h[1] = (__bf16)((v1 - m) * r * gv.y + bv.y);
        *(unsigned*)(Xb + base + 2 * t) = pk.u;
    }
    fill_slice(smf, S4, C4, bid, 8704);
}

// ---------------- k5: out2 = X @ Wfold (bf16 out), 64x64 tiles; fill F5 ----------------
__global__ __launch_bounds__(256) void k5_gemm(const __bf16* __restrict__ X,
        const __bf16* __restrict__ WfT, __bf16* __restrict__ out2, f32x4* __restrict__ smf){
    const int bid = blockIdx.x;
    if (bid < 1024){                           // 128 x 8 tiles, K=512
        __shared__ __bf16 As[64 * 64];
        __shared__ __bf16 Bs[64 * 64];
        const int bm = (bid >> 3) * 64, bn = (bid & 7) * 64;
        f32x4 acc[2][2] = {};
        gemm_core<512>(X, WfT, bm, bn, As, Bs, acc);
        const int t = threadIdx.x, lane = t & 63, wave = t >> 6;
        const int wm = (wave >> 1) * 32, wn = (wave & 1) * 32;
        const int lm = lane & 15, lq = lane >> 4;
        #pragma unroll
        for (int mi = 0; mi < 2; ++mi)
          #pragma unroll
          for (int ni = 0; ni < 2; ++ni)
            #pragma unroll
            for (int r = 0; r < 4; ++r){
                int row = bm + wm + mi * 16 + lq * 4 + r;
                int col = bn + wn + ni * 16 + lm;
                out2[(size_t)row * 512 + col] = (__bf16)acc[mi][ni][r];
            }
    }
    fill_slice(smf, S5, C5, bid, 2048);
}

// ---------------- k6: ln2 + kv -> out3; fill F6 ----------------
__global__ __launch_bounds__(256) void k6_ln2(const __bf16* __restrict__ X,
        const __bf16* __restrict__ o2, const float* __restrict__ fb,
        const float* __restrict__ g2, const float* __restrict__ b2,
        const float* __restrict__ keyval, float* __restrict__ out3,
        f32x4* __restrict__ smf){
    __shared__ float sh[8];
    const int bid = blockIdx.x, t = threadIdx.x;
    if (bid < 8192){
        const int b = bid >> 11;
        const size_t base = (size_t)bid * 512;
        union { unsigned u; __bf16 h[2]; } xv, yv;
        xv.u = *(const unsigned*)(X + base + 2 * t);
        yv.u = *(const unsigned*)(o2 + base + 2 * t);
        float2 fv = *(const float2*)(fb + 2 * t);   // fb already includes b2b
        float v0 = (float)xv.h[0] + (float)yv.h[0] + fv.x;
        float v1 = (float)xv.h[1] + (float)yv.h[1] + fv.y;
        float s = v0 + v1, ss = v0 * v0 + v1 * v1;
        for (int off = 32; off; off >>= 1){ s += __shfl_down(s, off); ss += __shfl_down(ss, off); }
        int wv = t >> 6, ln = t & 63;
        if (ln == 0){ sh[wv] = s; sh[4 + wv] = ss; }
        __syncthreads();
        if (t == 0){
            float S  = sh[0] + sh[1] + sh[2] + sh[3];
            float SS = sh[4] + sh[5] + sh[6] + sh[7];
            float m = S * (1.0f / 512.0f);
            float var = SS * (1.0f / 512.0f) - m * m;
            sh[0] = m; sh[1] = rsqrtf(var + 1e-5f);
        }
        __syncthreads();
        float m = sh[0], r = sh[1];
        float2 gv = *(const float2*)(g2 + 2 * t);
        float2 bv = *(const float2*)(b2 + 2 * t);
        float2 kv = *(const float2*)(keyval + (size_t)b * 512 + 2 * t);
        float y0 = (v0 - m) * r * gv.x + bv.x + kv.x;
        float y1 = (v1 - m) * r * gv.y + bv.y + kv.y;
        *(float2*)(out3 + base + 2 * t) = make_float2(y0, y1);
    }
    fill_slice(smf, S6, C6, bid, 8704);
}

// ---------------- launch ----------------
extern "C" void kernel_launch(void* const* d_in, const int* in_sizes, int n_in,
                              void* d_out, int out_size, void* d_ws, size_t ws_size,
                              hipStream_t stream){
    const float* query  = (const float*)d_in[0];
    const float* keyval = (const float*)d_in[1];
    // d_in[2] Wq, d_in[3] bq: provably unused (softmax is uniform regardless of Q)
    const float* Wkv = (const float*)d_in[4];
    const float* bkv = (const float*)d_in[5];
    const float* Wff = (const float*)d_in[6];
    const float* bff = (const float*)d_in[7];
    const float* g1  = (const float*)d_in[8];
    const float* b1  = (const float*)d_in[9];
    const float* W2a = (const float*)d_in[10];
    const float* b2a = (const float*)d_in[11];
    const float* W2b = (const float*)d_in[12];
    const float* b2b = (const float*)d_in[13];
    const float* g2  = (const float*)d_in[14];
    const float* b2  = (const float*)d_in[15];

    float* out3 = (float*)d_out;
    f32x4* smf  = (f32x4*)(out3 + OUT3_N);

    // scratch (~21.8 MB): prefer d_ws; fall back to the sm region (never hit in practice)
    char* base = (ws_size >= (64ull << 20)) ? (char*)d_ws : (char*)smf;
    __bf16* t_A1   = (__bf16*)base;                     // [576][2048]
    __bf16* t_W2bT = t_A1 + 1179648;                    // [512][2048]
    __bf16* t_WfT  = t_W2bT + 1048576;                  // [512][512] (transposed Wfold, bf16)
    __bf16* t_X    = t_WfT + 262144;                    // [8192][512]
    __bf16* t_out2 = t_X + 4194304;                     // [8192][512] bf16
    float*  t_V    = (float*)(t_out2 + 4194304);        // [4][1200]
    float*  t_oc   = t_V + 4800;                        // [4][512]
    float*  t_fb   = t_oc + 2048;                       // [512] = b2a@W2b + b2b (fp32)

    k1_prep<<<2848, 256, 0, stream>>>(W2a, b2a, t_A1, W2b, t_W2bT,
                                      keyval, Wkv, bkv, t_V, smf);
    k3_wf_oc<<<2048, 256, 0, stream>>>(t_A1, t_W2bT, t_WfT, t_fb, b2b,
                                       t_V, Wff, bff, t_oc, smf);
    k4_ln1<<<8704, 256, 0, stream>>>(query, t_oc, g1, b1, t_X, smf);
    k5_gemm<<<2048, 256, 0, stream>>>(t_X, t_WfT, t_out2, smf);
    k6_ln2<<<8704, 256, 0, stream>>>(t_X, t_out2, t_fb, g2, b2,
                                     keyval, out3, smf);
}

// Round 3
// 538.488 us; speedup vs baseline: 1.0028x; 1.0028x over previous
//
#include <hip/hip_runtime.h>
#include <hip/hip_bf16.h>

// Problem constants (B=4, L=2048, D=512, M=1200, H=6)
// KEY INSIGHT: keyval is broadcast over L -> K rows identical -> softmax == 1/L exactly,
// mha == V[b] (per-batch constant), and leaky(slope=1) is identity so W2a@W2b folds.
// R11 = R10 + latency fixes. R9/R10's +51us vs R8 was traced to three de-parallelized
// latency chains (V 64 waits, oc 75 waits, WfGEMM 32 vmcnt(0) drains with 72 blocks =
// no TLP). Fixes: V wave-d-split (16 waits), oc 8-wave m-split unroll 15 (10 waits),
// WfGEMM 8-wave in-block split-K (16 waits/half, lockstep barriers, LDS reduce).
// Still: 5 dispatches, no memset, no atomics, WfT bf16 written directly by k3.

typedef __bf16 bf16x8 __attribute__((ext_vector_type(8)));
typedef float f32x4 __attribute__((ext_vector_type(4)));

constexpr size_t OUT3_N = 4ull * 2048 * 512;            // 4,194,304
constexpr size_t SM_N4  = (4ull * 6 * 2048 * 2048) / 4; // 25,165,824 f32x4
constexpr float  SMV    = 1.0f / 2048.0f;

// fill slice schedule (f32x4 units) — disjoint, covers SM exactly (R8-balanced)
constexpr size_t S1 = 0,        C1 = 5375000;
constexpr size_t S3 = 5375000,  C3 = 5687500;
constexpr size_t S4 = 11062500, C4 = 4750000;
constexpr size_t S5 = 15812500, C5 = 5187500;
constexpr size_t S6 = 21000000, C6 = 4165824;
static_assert(S6 + C6 == SM_N4, "fill slices must cover sm");

template<int T>
__device__ __forceinline__ void fill_sliceT(f32x4* __restrict__ p, size_t base, size_t cnt,
                                            int fb, int nfb){
    const f32x4 v = { SMV, SMV, SMV, SMV };
    const size_t stride = (size_t)nfb * T;
    for (size_t j = (size_t)fb * T + threadIdx.x; j < cnt; j += stride)
        __builtin_nontemporal_store(v, p + base + j);
}

// ---------------- 256-thread 64x64 MFMA tile core (BK=64, 4 waves 2x2, swizzled LDS) ----
template<int KDIM>
__device__ __forceinline__ void gemm_core(const __bf16* __restrict__ A,
        const __bf16* __restrict__ BT, int bm, int bn,
        __bf16* As, __bf16* Bs, f32x4 (&acc)[2][2]){
    const int tid = threadIdx.x, wave = tid >> 6, lane = tid & 63;
    const int r_st = wave * 8 + (lane >> 3);
    const int c8g  = (lane & 7) ^ (r_st & 7);
    const __bf16* Ag = A  + (size_t)(bm + r_st) * KDIM + c8g * 8;
    const __bf16* Bg = BT + (size_t)(bn + r_st) * KDIM + c8g * 8;
    const size_t rowskip = (size_t)32 * KDIM;
    const int wm = (wave >> 1) * 32, wn = (wave & 1) * 32;
    const int lm = lane & 15, lq = lane >> 4;
    for (int k0 = 0; k0 < KDIM; k0 += 64){
        __builtin_amdgcn_global_load_lds(
            (const __attribute__((address_space(1))) void*)(Ag + k0),
            (__attribute__((address_space(3))) void*)&As[wave * 512], 16, 0, 0);
        __builtin_amdgcn_global_load_lds(
            (const __attribute__((address_space(1))) void*)(Ag + k0 + rowskip),
            (__attribute__((address_space(3))) void*)&As[2048 + wave * 512], 16, 0, 0);
        __builtin_amdgcn_global_load_lds(
            (const __attribute__((address_space(1))) void*)(Bg + k0),
            (__attribute__((address_space(3))) void*)&Bs[wave * 512], 16, 0, 0);
        __builtin_amdgcn_global_load_lds(
            (const __attribute__((address_space(1))) void*)(Bg + k0 + rowskip),
            (__attribute__((address_space(3))) void*)&Bs[2048 + wave * 512], 16, 0, 0);
        __syncthreads();
        #pragma unroll
        for (int kb = 0; kb < 64; kb += 32){
            const int sw = (((kb >> 3) + lq) ^ (lm & 7)) << 3;
            bf16x8 a0 = *(const bf16x8*)&As[(wm + lm) * 64 + sw];
            bf16x8 a1 = *(const bf16x8*)&As[(wm + 16 + lm) * 64 + sw];
            bf16x8 b0 = *(const bf16x8*)&Bs[(wn + lm) * 64 + sw];
            bf16x8 b1 = *(const bf16x8*)&Bs[(wn + 16 + lm) * 64 + sw];
            acc[0][0] = __builtin_amdgcn_mfma_f32_16x16x32_bf16(a0, b0, acc[0][0], 0, 0, 0);
            acc[0][1] = __builtin_amdgcn_mfma_f32_16x16x32_bf16(a0, b1, acc[0][1], 0, 0, 0);
            acc[1][0] = __builtin_amdgcn_mfma_f32_16x16x32_bf16(a1, b0, acc[1][0], 0, 0, 0);
            acc[1][1] = __builtin_amdgcn_mfma_f32_16x16x32_bf16(a1, b1, acc[1][1], 0, 0, 0);
        }
        __syncthreads();
    }
}

// ---------------- k1: A1 cast, W2b transpose, V wave-d-split GEMV; fill F1 ----------------
__global__ __launch_bounds__(256) void k1_prep(const float* __restrict__ W2a,
        const float* __restrict__ b2a, __bf16* __restrict__ A1,
        const float* __restrict__ W2b, __bf16* __restrict__ W2bT,
        const float* __restrict__ keyval, const float* __restrict__ Wkv,
        const float* __restrict__ bkv, float* __restrict__ V, f32x4* __restrict__ smf){
    __shared__ float sh[32 * 33];
    const int bid = blockIdx.x, tid = threadIdx.x;
    if (bid < 1152){
        int r = bid >> 1;
        int c = (bid & 1) * 1024 + tid * 4;
        float4 v;
        if (r < 512)       v = *(const float4*)(W2a + (size_t)r * 2048 + c);
        else if (r == 512) v = *(const float4*)(b2a + c);
        else               v = make_float4(0.f, 0.f, 0.f, 0.f);
        __bf16* o = A1 + (size_t)r * 2048 + c;
        o[0] = (__bf16)v.x; o[1] = (__bf16)v.y; o[2] = (__bf16)v.z; o[3] = (__bf16)v.w;
    } else if (bid < 2176){
        int t = bid - 1152;                    // 1024 tiles over W2b [2048][512]
        int c0 = (t & 15) * 32, r0 = (t >> 4) * 32;
        int tx = tid & 31, ty = tid >> 5;
        for (int i = ty; i < 32; i += 8)
            sh[i * 33 + tx] = W2b[(size_t)(r0 + i) * 512 + c0 + tx];
        __syncthreads();
        for (int i = ty; i < 32; i += 8)
            W2bT[(size_t)(c0 + i) * 2048 + r0 + tx] = (__bf16)sh[tx * 33 + i];
    } else if (bid < 2196){
        // V[b][mc*240..+240): 4 waves split d=512 into 128 each -> 16 latency rounds
        int i = bid - 2176;                    // 20: b(4) x mc(5)
        int b = i & 3, mc = i >> 2;
        int w = tid >> 6, lane = tid & 63;
        const float* kvb = keyval + (size_t)b * 512;
        float a0 = 0.f, a1 = 0.f, a2 = 0.f, a3 = 0.f;
        #pragma unroll 8
        for (int d = 0; d < 128; ++d){
            float kv = kvb[w * 128 + d];
            const float* row = Wkv + (size_t)(w * 128 + d) * 2400 + 1200 + mc * 240;
            a0 += kv * row[lane];
            a1 += kv * row[64 + lane];
            a2 += kv * row[128 + lane];
            if (lane < 48) a3 += kv * row[192 + lane];
        }
        float* pv = sh;                        // 4*240 = 960 floats (fits 32*33)
        pv[w * 240 + lane] = a0;
        pv[w * 240 + 64 + lane] = a1;
        pv[w * 240 + 128 + lane] = a2;
        if (lane < 48) pv[w * 240 + 192 + lane] = a3;
        __syncthreads();
        if (tid < 240){
            float s = bkv[1200 + mc * 240 + tid]
                    + pv[tid] + pv[240 + tid] + pv[480 + tid] + pv[720 + tid];
            V[b * 1200 + mc * 240 + tid] = s;
        }
    }
    fill_sliceT<256>(smf, S1, C1, bid, 2848);
}

// ---------------- k3 (512 threads): Wfold 8-wave split-K GEMM -> WfT bf16 + fb;
//                  oc 8-wave m-split GEMV; fill F3 ----------------
__global__ __launch_bounds__(512) void k3_wf_oc(const __bf16* __restrict__ A1,
        const __bf16* __restrict__ W2bT, __bf16* __restrict__ WfT,
        float* __restrict__ fb, const float* __restrict__ b2b,
        const float* __restrict__ V, const float* __restrict__ Wff,
        const float* __restrict__ bff, float* __restrict__ oc, f32x4* __restrict__ smf){
    const int bid = blockIdx.x, t = threadIdx.x;
    if (bid < 72){                             // 9 row-tiles x 8 col-tiles
        __shared__ __bf16 As[2][64 * 64];
        __shared__ __bf16 Bs[2][64 * 64];
        const int bm = (bid % 9) * 64, bn = (bid / 9) * 64;
        const int wave = t >> 6, lane = t & 63;
        const int kh = wave >> 2, ws = wave & 3;   // K-half, sub-wave
        const int r_st = ws * 8 + (lane >> 3);
        const int c8g  = (lane & 7) ^ (r_st & 7);
        const __bf16* Ag = A1   + (size_t)(bm + r_st) * 2048 + kh * 1024 + c8g * 8;
        const __bf16* Bg = W2bT + (size_t)(bn + r_st) * 2048 + kh * 1024 + c8g * 8;
        const size_t rowskip = (size_t)32 * 2048;
        const int wm = (ws >> 1) * 32, wn = (ws & 1) * 32;
        const int lm = lane & 15, lq = lane >> 4;
        f32x4 acc[2][2] = {};
        for (int k0 = 0; k0 < 1024; k0 += 64){  // 16 lockstep steps per half
            __builtin_amdgcn_global_load_lds(
                (const __attribute__((address_space(1))) void*)(Ag + k0),
                (__attribute__((address_space(3))) void*)&As[kh][ws * 512], 16, 0, 0);
            __builtin_amdgcn_global_load_lds(
                (const __attribute__((address_space(1))) void*)(Ag + k0 + rowskip),
                (__attribute__((address_space(3))) void*)&As[kh][2048 + ws * 512], 16, 0, 0);
            __builtin_amdgcn_global_load_lds(
                (const __attribute__((address_space(1))) void*)(Bg + k0),
                (__attribute__((address_space(3))) void*)&Bs[kh][ws * 512], 16, 0, 0);
            __builtin_amdgcn_global_load_lds(
                (const __attribute__((address_space(1))) void*)(Bg + k0 + rowskip),
                (__attribute__((address_space(3))) void*)&Bs[kh][2048 + ws * 512], 16, 0, 0);
            __syncthreads();
            #pragma unroll
            for (int kb = 0; kb < 64; kb += 32){
                const int sw = (((kb >> 3) + lq) ^ (lm & 7)) << 3;
                bf16x8 a0 = *(const bf16x8*)&As[kh][(wm + lm) * 64 + sw];
                bf16x8 a1 = *(const bf16x8*)&As[kh][(wm + 16 + lm) * 64 + sw];
                bf16x8 b0 = *(const bf16x8*)&Bs[kh][(wn + lm) * 64 + sw];
                bf16x8 b1 = *(const bf16x8*)&Bs[kh][(wn + 16 + lm) * 64 + sw];
                acc[0][0] = __builtin_amdgcn_mfma_f32_16x16x32_bf16(a0, b0, acc[0][0], 0, 0, 0);
                acc[0][1] = __builtin_amdgcn_mfma_f32_16x16x32_bf16(a0, b1, acc[0][1], 0, 0, 0);
                acc[1][0] = __builtin_amdgcn_mfma_f32_16x16x32_bf16(a1, b0, acc[1][0], 0, 0, 0);
                acc[1][1] = __builtin_amdgcn_mfma_f32_16x16x32_bf16(a1, b1, acc[1][1], 0, 0, 0);
            }
            __syncthreads();
        }
        // cross-half reduction: kh=1 stores 16 floats/lane (16 KB = As), kh=0 adds
        float* red = (float*)&As[0][0];
        if (kh == 1){
            #pragma unroll
            for (int mi = 0; mi < 2; ++mi)
              #pragma unroll
              for (int ni = 0; ni < 2; ++ni)
                *(f32x4*)&red[(ws * 64 + lane) * 16 + (mi * 2 + ni) * 4] = acc[mi][ni];
        }
        __syncthreads();
        if (kh == 0){
            #pragma unroll
            for (int mi = 0; mi < 2; ++mi)
              #pragma unroll
              for (int ni = 0; ni < 2; ++ni){
                f32x4 o = *(const f32x4*)&red[(ws * 64 + lane) * 16 + (mi * 2 + ni) * 4];
                acc[mi][ni] += o;
              }
            #pragma unroll
            for (int mi = 0; mi < 2; ++mi)
              #pragma unroll
              for (int ni = 0; ni < 2; ++ni)
                #pragma unroll
                for (int r = 0; r < 4; ++r){
                    int row = bm + wm + mi * 16 + lq * 4 + r;   // C/D: row=(lane>>4)*4+reg
                    int col = bn + wn + ni * 16 + lm;           //      col=lane&15
                    if (row < 512)       WfT[(size_t)col * 512 + row] = (__bf16)acc[mi][ni][r];
                    else if (row == 512) fb[col] = acc[mi][ni][r] + b2b[col];
                }
        }
    } else if (bid < 104){                     // oc: b(4) x jc(8); 8 waves split m=1200
        __shared__ float sh[8 * 64];
        int i = bid - 72;
        int b = i & 3, jc = i >> 2;
        int w = t >> 6, j = jc * 64 + (t & 63);
        const float* vb = V + b * 1200;
        float acc = 0.f;
        int m0 = w * 150;
        #pragma unroll 15
        for (int m = m0; m < m0 + 150; ++m)
            acc += vb[m] * Wff[(size_t)m * 512 + j];
        sh[t] = acc;
        __syncthreads();
        if (t < 64){
            float s = bff[jc * 64 + t];
            #pragma unroll
            for (int w2 = 0; w2 < 8; ++w2) s += sh[w2 * 64 + t];
            oc[b * 512 + jc * 64 + t] = s;
        }
    }
    fill_sliceT<512>(smf, S3, C3, bid, 2048);
}

// ---------------- k4: ln1 -> X bf16; fill F4 ----------------
__global__ __launch_bounds__(256) void k4_ln1(const float* __restrict__ q,
        const float* __restrict__ oc, const float* __restrict__ g1,
        const float* __restrict__ b1, __bf16* __restrict__ Xb, f32x4* __restrict__ smf){
    __shared__ float sh[8];
    const int bid = blockIdx.x, t = threadIdx.x;
    if (bid < 8192){
        const int b = bid >> 11;
        const size_t base = (size_t)bid * 512;
        float2 qv = *(const float2*)(q + base + 2 * t);
        float2 ov = *(const float2*)(oc + (size_t)b * 512 + 2 * t);
        float v0 = qv.x + ov.x, v1 = qv.y + ov.y;
        float s = v0 + v1, ss = v0 * v0 + v1 * v1;
        for (int off = 32; off; off >>= 1){ s += __shfl_down(s, off); ss += __shfl_down(ss, off); }
        int wv = t >> 6, ln = t & 63;
        if (ln == 0){ sh[wv] = s; sh[4 + wv] = ss; }
        __syncthreads();
        if (t == 0){
            float S  = sh[0] + sh[1] + sh[2] + sh[3];
            float SS = sh[4] + sh[5] + sh[6] + sh[7];
            float m = S * (1.0f / 512.0f);
            float var = SS * (1.0f / 512.0f) - m * m;
            sh[0] = m; sh[1] = rsqrtf(var + 1e-5f);
        }
        __syncthreads();
        float m = sh[0], r = sh[1];
        float2 gv = *(const float2*)(g1 + 2 * t);
        float2 bv = *(const float2*)(b1 + 2 * t);
        union { __bf16 h[2]; unsigned u; } pk;
        pk.h[0] = (__bf16)((v0 - m) * r * gv.x + bv.x);
        pk.h[1] = (__bf16)((v1 - m) * r * gv.y + bv.y);
        *(unsigned*)(Xb + base + 2 * t) = pk.u;
    }
    fill_sliceT<256>(smf, S4, C4, bid, 8704);
}

// ---------------- k5: out2 = X @ Wfold (bf16 out), 64x64 tiles; fill F5 ----------------
__global__ __launch_bounds__(256) void k5_gemm(const __bf16* __restrict__ X,
        const __bf16* __restrict__ WfT, __bf16* __restrict__ out2, f32x4* __restrict__ smf){
    const int bid = blockIdx.x;
    if (bid < 1024){                           // 128 x 8 tiles, K=512
        __shared__ __bf16 As[64 * 64];
        __shared__ __bf16 Bs[64 * 64];
        const int bm = (bid >> 3) * 64, bn = (bid & 7) * 64;
        f32x4 acc[2][2] = {};
        gemm_core<512>(X, WfT, bm, bn, As, Bs, acc);
        const int t = threadIdx.x, lane = t & 63, wave = t >> 6;
        const int wm = (wave >> 1) * 32, wn = (wave & 1) * 32;
        const int lm = lane & 15, lq = lane >> 4;
        #pragma unroll
        for (int mi = 0; mi < 2; ++mi)
          #pragma unroll
          for (int ni = 0; ni < 2; ++ni)
            #pragma unroll
            for (int r = 0; r < 4; ++r){
                int row = bm + wm + mi * 16 + lq * 4 + r;
                int col = bn + wn + ni * 16 + lm;
                out2[(size_t)row * 512 + col] = (__bf16)acc[mi][ni][r];
            }
    }
    fill_sliceT<256>(smf, S5, C5, bid, 2048);
}

// ---------------- k6: ln2 + kv -> out3; fill F6 ----------------
__global__ __launch_bounds__(256) void k6_ln2(const __bf16* __restrict__ X,
        const __bf16* __restrict__ o2, const float* __restrict__ fb,
        const float* __restrict__ g2, const float* __restrict__ b2,
        const float* __restrict__ keyval, float* __restrict__ out3,
        f32x4* __restrict__ smf){
    __shared__ float sh[8];
    const int bid = blockIdx.x, t = threadIdx.x;
    if (bid < 8192){
        const int b = bid >> 11;
        const size_t base = (size_t)bid * 512;
        union { unsigned u; __bf16 h[2]; } xv, yv;
        xv.u = *(const unsigned*)(X + base + 2 * t);
        yv.u = *(const unsigned*)(o2 + base + 2 * t);
        float2 fv = *(const float2*)(fb + 2 * t);   // fb already includes b2b
        float v0 = (float)xv.h[0] + (float)yv.h[0] + fv.x;
        float v1 = (float)xv.h[1] + (float)yv.h[1] + fv.y;
        float s = v0 + v1, ss = v0 * v0 + v1 * v1;
        for (int off = 32; off; off >>= 1){ s += __shfl_down(s, off); ss += __shfl_down(ss, off); }
        int wv = t >> 6, ln = t & 63;
        if (ln == 0){ sh[wv] = s; sh[4 + wv] = ss; }
        __syncthreads();
        if (t == 0){
            float S  = sh[0] + sh[1] + sh[2] + sh[3];
            float SS = sh[4] + sh[5] + sh[6] + sh[7];
            float m = S * (1.0f / 512.0f);
            float var = SS * (1.0f / 512.0f) - m * m;
            sh[0] = m; sh[1] = rsqrtf(var + 1e-5f);
        }
        __syncthreads();
        float m = sh[0], r = sh[1];
        float2 gv = *(const float2*)(g2 + 2 * t);
        float2 bv = *(const float2*)(b2 + 2 * t);
        float2 kv = *(const float2*)(keyval + (size_t)b * 512 + 2 * t);
        float y0 = (v0 - m) * r * gv.x + bv.x + kv.x;
        float y1 = (v1 - m) * r * gv.y + bv.y + kv.y;
        *(float2*)(out3 + base + 2 * t) = make_float2(y0, y1);
    }
    fill_sliceT<256>(smf, S6, C6, bid, 8704);
}

// ---------------- launch ----------------
extern "C" void kernel_launch(void* const* d_in, const int* in_sizes, int n_in,
                              void* d_out, int out_size, void* d_ws, size_t ws_size,
                              hipStream_t stream){
    const float* query  = (const float*)d_in[0];
    const float* keyval = (const float*)d_in[1];
    // d_in[2] Wq, d_in[3] bq: provably unused (softmax is uniform regardless of Q)
    const float* Wkv = (const float*)d_in[4];
    const float* bkv = (const float*)d_in[5];
    const float* Wff = (const float*)d_in[6];
    const float* bff = (const float*)d_in[7];
    const float* g1  = (const float*)d_in[8];
    const float* b1  = (const float*)d_in[9];
    const float* W2a = (const float*)d_in[10];
    const float* b2a = (const float*)d_in[11];
    const float* W2b = (const float*)d_in[12];
    const float* b2b = (const float*)d_in[13];
    const float* g2  = (const float*)d_in[14];
    const float* b2  = (const float*)d_in[15];

    float* out3 = (float*)d_out;
    f32x4* smf  = (f32x4*)(out3 + OUT3_N);

    // scratch (~21.8 MB): prefer d_ws; fall back to the sm region (never hit in practice)
    char* base = (ws_size >= (64ull << 20)) ? (char*)d_ws : (char*)smf;
    __bf16* t_A1   = (__bf16*)base;                     // [576][2048]
    __bf16* t_W2bT = t_A1 + 1179648;                    // [512][2048]
    __bf16* t_WfT  = t_W2bT + 1048576;                  // [512][512] (transposed Wfold, bf16)
    __bf16* t_X    = t_WfT + 262144;                    // [8192][512]
    __bf16* t_out2 = t_X + 4194304;                     // [8192][512] bf16
    float*  t_V    = (float*)(t_out2 + 4194304);        // [4][1200]
    float*  t_oc   = t_V + 4800;                        // [4][512]
    float*  t_fb   = t_oc + 2048;                       // [512] = b2a@W2b + b2b (fp32)

    k1_prep<<<2848, 256, 0, stream>>>(W2a, b2a, t_A1, W2b, t_W2bT,
                                      keyval, Wkv, bkv, t_V, smf);
    k3_wf_oc<<<2048, 512, 0, stream>>>(t_A1, t_W2bT, t_WfT, t_fb, b2b,
                                       t_V, Wff, bff, t_oc, smf);
    k4_ln1<<<8704, 256, 0, stream>>>(query, t_oc, g1, b1, t_X, smf);
    k5_gemm<<<2048, 256, 0, stream>>>(t_X, t_WfT, t_out2, smf);
    k6_ln2<<<8704, 256, 0, stream>>>(t_X, t_out2, t_fb, g2, b2,
                                     keyval, out3, smf);
}

// Round 4
// 485.153 us; speedup vs baseline: 1.1130x; 1.1099x over previous
//
#include <hip/hip_runtime.h>
#include <hip/hip_bf16.h>

// Problem constants (B=4, L=2048, D=512, M=1200, H=6)
// KEY INSIGHT: keyval is broadcast over L -> K rows identical -> softmax == 1/L exactly,
// mha == V[b] (per-batch constant), and leaky(slope=1) is identity so W2a@W2b folds.
// R12 = R8 re-anchor (R9/R10/R11 all regressed +51us for reasons invisible in top-5
// counters and insensitive to k3/k5/k6 restructuring; reverting to the proven 488us
// structure). Two strictly-local edits on top of R8:
//   (1) k5 tiles 64x64 -> 64x128 (512 work blocks): halves X A-panel re-reads.
//   (2) k1 A1-cast uses one packed 8B store instead of 4 scalar bf16 stores.
// Everything else (memset, split-K atomics, grids, fill slices) is R8-identical.

typedef __bf16 bf16x8 __attribute__((ext_vector_type(8)));
typedef float f32x4 __attribute__((ext_vector_type(4)));

constexpr size_t OUT3_N = 4ull * 2048 * 512;            // 4,194,304
constexpr size_t SM_N4  = (4ull * 6 * 2048 * 2048) / 4; // 25,165,824 f32x4
constexpr float  SMV    = 1.0f / 2048.0f;

// fill slice schedule (f32x4 units) — disjoint, covers SM exactly
constexpr size_t S1 = 0,        C1 = 5375000;
constexpr size_t S3 = 5375000,  C3 = 5687500;
constexpr size_t S4 = 11062500, C4 = 4750000;
constexpr size_t S5 = 15812500, C5 = 5187500;
constexpr size_t S6 = 21000000, C6 = 4165824;
static_assert(S6 + C6 == SM_N4, "fill slices must cover sm");

__device__ __forceinline__ void fill_slice(f32x4* __restrict__ p, size_t base, size_t cnt,
                                           int fb, int nfb){
    const f32x4 v = { SMV, SMV, SMV, SMV };
    const size_t stride = (size_t)nfb * 256;
    for (size_t j = (size_t)fb * 256 + threadIdx.x; j < cnt; j += stride)
        __builtin_nontemporal_store(v, p + base + j);
}

// ---------------- bf16 MFMA GEMM tile: C[64x64 at bm,bn] (+)= A[M,K] @ BT[N,K]^T over [k0beg,k0end)
// BK=64, 4 waves 2x2, global_load_lds width16, XOR-swizzled LDS (16B chunks: c8' = c8 ^ (r&7))
// MODE: 1 = atomicAdd fp32 (split-K), 2 = store bf16
template<int MODE, typename OutT>
__device__ void gemm_tile(const __bf16* __restrict__ A, const __bf16* __restrict__ BT,
                          OutT* __restrict__ C, int Ndim, int Kdim,
                          int bm, int bn, int k0beg, int k0end){
    __shared__ __bf16 As[64 * 64];
    __shared__ __bf16 Bs[64 * 64];
    const int tid = threadIdx.x, wave = tid >> 6, lane = tid & 63;
    const int r_st = wave * 8 + (lane >> 3);
    const int c8g  = (lane & 7) ^ (r_st & 7);
    const __bf16* Ag = A  + (size_t)(bm + r_st) * Kdim + c8g * 8;
    const __bf16* Bg = BT + (size_t)(bn + r_st) * Kdim + c8g * 8;
    const size_t rowskip = (size_t)32 * Kdim;
    const int wm = (wave >> 1) * 32, wn = (wave & 1) * 32;
    const int lm = lane & 15, lq = lane >> 4;
    f32x4 acc[2][2] = {};
    for (int k0 = k0beg; k0 < k0end; k0 += 64){
        __builtin_amdgcn_global_load_lds(
            (const __attribute__((address_space(1))) void*)(Ag + k0),
            (__attribute__((address_space(3))) void*)&As[wave * 512], 16, 0, 0);
        __builtin_amdgcn_global_load_lds(
            (const __attribute__((address_space(1))) void*)(Ag + k0 + rowskip),
            (__attribute__((address_space(3))) void*)&As[2048 + wave * 512], 16, 0, 0);
        __builtin_amdgcn_global_load_lds(
            (const __attribute__((address_space(1))) void*)(Bg + k0),
            (__attribute__((address_space(3))) void*)&Bs[wave * 512], 16, 0, 0);
        __builtin_amdgcn_global_load_lds(
            (const __attribute__((address_space(1))) void*)(Bg + k0 + rowskip),
            (__attribute__((address_space(3))) void*)&Bs[2048 + wave * 512], 16, 0, 0);
        __syncthreads();
        #pragma unroll
        for (int kb = 0; kb < 64; kb += 32){
            const int sw = (((kb >> 3) + lq) ^ (lm & 7)) << 3;
            bf16x8 a0 = *(const bf16x8*)&As[(wm + lm) * 64 + sw];
            bf16x8 a1 = *(const bf16x8*)&As[(wm + 16 + lm) * 64 + sw];
            bf16x8 b0 = *(const bf16x8*)&Bs[(wn + lm) * 64 + sw];
            bf16x8 b1 = *(const bf16x8*)&Bs[(wn + 16 + lm) * 64 + sw];
            acc[0][0] = __builtin_amdgcn_mfma_f32_16x16x32_bf16(a0, b0, acc[0][0], 0, 0, 0);
            acc[0][1] = __builtin_amdgcn_mfma_f32_16x16x32_bf16(a0, b1, acc[0][1], 0, 0, 0);
            acc[1][0] = __builtin_amdgcn_mfma_f32_16x16x32_bf16(a1, b0, acc[1][0], 0, 0, 0);
            acc[1][1] = __builtin_amdgcn_mfma_f32_16x16x32_bf16(a1, b1, acc[1][1], 0, 0, 0);
        }
        __syncthreads();
    }
    #pragma unroll
    for (int mi = 0; mi < 2; ++mi)
      #pragma unroll
      for (int ni = 0; ni < 2; ++ni)
        #pragma unroll
        for (int r = 0; r < 4; ++r){
            int row = bm + wm + mi * 16 + lq * 4 + r;   // C/D: row=(lane>>4)*4+reg
            int col = bn + wn + ni * 16 + lm;           //      col=lane&15
            if (MODE == 1) atomicAdd((float*)&C[(size_t)row * Ndim + col], acc[mi][ni][r]);
            else           C[(size_t)row * Ndim + col] = (OutT)acc[mi][ni][r];
        }
}

// ---------------- k1: prep + kv split-K; ALL blocks then fill their C1 share ----------------
__global__ __launch_bounds__(256) void k1_prep_kv(const float* __restrict__ W2a,
        const float* __restrict__ b2a, __bf16* __restrict__ A1,
        const float* __restrict__ W2b, __bf16* __restrict__ W2bT,
        const float* __restrict__ keyval, const float* __restrict__ Wkv,
        const float* __restrict__ bkv, float* __restrict__ V, f32x4* __restrict__ smf){
    __shared__ float sh[32 * 33];
    const int bid = blockIdx.x, tid = threadIdx.x;
    if (bid < 1152){
        int r = bid >> 1;
        int c = (bid & 1) * 1024 + tid * 4;
        float4 v;
        if (r < 512)       v = *(const float4*)(W2a + (size_t)r * 2048 + c);
        else if (r == 512) v = *(const float4*)(b2a + c);
        else               v = make_float4(0.f, 0.f, 0.f, 0.f);
        union { __bf16 h[4]; ushort4 u; } pk;
        pk.h[0] = (__bf16)v.x; pk.h[1] = (__bf16)v.y;
        pk.h[2] = (__bf16)v.z; pk.h[3] = (__bf16)v.w;
        *(ushort4*)(A1 + (size_t)r * 2048 + c) = pk.u;
    } else if (bid < 2176){
        int t = bid - 1152;                    // 1024 tiles over W2b [2048][512]
        int c0 = (t & 15) * 32, r0 = (t >> 4) * 32;
        int tx = tid & 31, ty = tid >> 5;
        for (int i = ty; i < 32; i += 8)
            sh[i * 33 + tx] = W2b[(size_t)(r0 + i) * 512 + c0 + tx];
        __syncthreads();
        for (int i = ty; i < 32; i += 8)
            W2bT[(size_t)(c0 + i) * 2048 + r0 + tx] = (__bf16)sh[tx * 33 + i];
    } else if (bid < 2336){
        int i = bid - 2176;                    // 160: b(4) x mc(5) x kc(8)
        int b = i & 3, mc = (i >> 2) % 5, kc = i / 20;
        int m = mc * 256 + tid;
        if (m < 1200){
            float acc = (kc == 0) ? bkv[1200 + m] : 0.f;
            const float* kvb = keyval + (size_t)b * 512;
            int d0 = kc * 64;
            #pragma unroll 8
            for (int d = d0; d < d0 + 64; ++d)
                acc += kvb[d] * Wkv[(size_t)d * 2400 + 1200 + m];
            atomicAdd(&V[b * 1200 + m], acc);
        }
    }
    fill_slice(smf, S1, C1, bid, 2848);
}

// ---------------- k3: fold GEMM split-K + oc GEMV; ALL blocks fill C3 share ----------------
__global__ __launch_bounds__(256) void k3_fold_oc(const __bf16* __restrict__ A1,
        const __bf16* __restrict__ W2bT, float* __restrict__ Wf,
        const float* __restrict__ V, const float* __restrict__ Wff,
        const float* __restrict__ bff, float* __restrict__ oc, f32x4* __restrict__ smf){
    const int bid = blockIdx.x, tid = threadIdx.x;
    if (bid < 288){                            // tile(9x8) x kc(4) over [576x512], K=2048
        int tile = bid % 72, kc = bid / 72;
        gemm_tile<1>(A1, W2bT, Wf, 512, 2048, (tile % 9) * 64, (tile / 9) * 64,
                     kc * 512, (kc + 1) * 512);
    } else if (bid < 384){                     // oc: b(4) x jc(2) x kc(12), K=1200
        int i = bid - 288;
        int b = i & 3, jc = (i >> 2) & 1, kc = i >> 3;
        int j = jc * 256 + tid;
        float acc = (kc == 0) ? bff[j] : 0.f;
        const float* vb = V + b * 1200;
        int m0 = kc * 100;
        #pragma unroll 5
        for (int m = m0; m < m0 + 100; ++m)
            acc += vb[m] * Wff[(size_t)m * 512 + j];
        atomicAdd(&oc[b * 512 + j], acc);
    }
    fill_slice(smf, S3, C3, bid, 2048);
}

// ---------------- k4: ln1 + tcast Wf->WfT; ALL blocks fill C4 share ----------------
__global__ __launch_bounds__(256) void k4_ln1_tcast(const float* __restrict__ q,
        const float* __restrict__ oc, const float* __restrict__ g1,
        const float* __restrict__ b1, __bf16* __restrict__ Xb,
        const float* __restrict__ Wf, __bf16* __restrict__ WfT, f32x4* __restrict__ smf){
    __shared__ float sh[32 * 33];
    const int bid = blockIdx.x, t = threadIdx.x;
    if (bid < 8192){
        const int b = bid >> 11;
        const size_t base = (size_t)bid * 512;
        float2 qv = *(const float2*)(q + base + 2 * t);
        float2 ov = *(const float2*)(oc + (size_t)b * 512 + 2 * t);
        float v0 = qv.x + ov.x, v1 = qv.y + ov.y;
        float s = v0 + v1, ss = v0 * v0 + v1 * v1;
        for (int off = 32; off; off >>= 1){ s += __shfl_down(s, off); ss += __shfl_down(ss, off); }
        int wv = t >> 6, ln = t & 63;
        if (ln == 0){ sh[wv] = s; sh[4 + wv] = ss; }
        __syncthreads();
        if (t == 0){
            float S  = sh[0] + sh[1] + sh[2] + sh[3];
            float SS = sh[4] + sh[5] + sh[6] + sh[7];
            float m = S * (1.0f / 512.0f);
            float var = SS * (1.0f / 512.0f) - m * m;
            sh[0] = m; sh[1] = rsqrtf(var + 1e-5f);
        }
        __syncthreads();
        float m = sh[0], r = sh[1];
        float2 gv = *(const float2*)(g1 + 2 * t);
        float2 bv = *(const float2*)(b1 + 2 * t);
        union { __bf16 h[2]; unsigned u; } pk;
        pk.h[0] = (__bf16)((v0 - m) * r * gv.x + bv.x);
        pk.h[1] = (__bf16)((v1 - m) * r * gv.y + bv.y);
        *(unsigned*)(Xb + base + 2 * t) = pk.u;
    } else if (bid < 8448){
        int tt = bid - 8192;                   // 256 tiles over Wf [512][512]
        int c0 = (tt & 15) * 32, r0 = (tt >> 4) * 32;
        int tx = t & 31, ty = t >> 5;
        for (int i = ty; i < 32; i += 8)
            sh[i * 33 + tx] = Wf[(size_t)(r0 + i) * 512 + c0 + tx];
        __syncthreads();
        for (int i = ty; i < 32; i += 8)
            WfT[(size_t)(c0 + i) * 512 + r0 + tx] = (__bf16)sh[tx * 33 + i];
    }
    fill_slice(smf, S4, C4, bid, 8960);
}

// ---------------- k5: main GEMM (out2 = X @ Wfold, bf16 out), 64x128 tiles ----------------
// 512 work blocks (128 m-tiles x 4 n-tiles): halves X A-panel re-reads vs 64x64.
__global__ __launch_bounds__(256) void k5_gemm(const __bf16* __restrict__ X,
        const __bf16* __restrict__ WfT, __bf16* __restrict__ out2, f32x4* __restrict__ smf){
    const int bid = blockIdx.x;
    if (bid < 512){
        __shared__ __bf16 As[64 * 64];         // 8 KB
        __shared__ __bf16 Bs[128 * 64];        // 16 KB
        const int bm = (bid >> 2) * 64, bn = (bid & 3) * 128;
        const int tid = threadIdx.x, wave = tid >> 6, lane = tid & 63;
        const int r_st = wave * 8 + (lane >> 3);
        const int c8g  = (lane & 7) ^ (r_st & 7);
        const __bf16* Ag = X   + (size_t)(bm + r_st) * 512 + c8g * 8;
        const __bf16* Bg = WfT + (size_t)(bn + r_st) * 512 + c8g * 8;
        const size_t rowskip = (size_t)32 * 512;
        const int wm = (wave >> 1) * 32, wn = (wave & 1) * 64;
        const int lm = lane & 15, lq = lane >> 4;
        f32x4 acc[2][4] = {};
        for (int k0 = 0; k0 < 512; k0 += 64){
            __builtin_amdgcn_global_load_lds(
                (const __attribute__((address_space(1))) void*)(Ag + k0),
                (__attribute__((address_space(3))) void*)&As[wave * 512], 16, 0, 0);
            __builtin_amdgcn_global_load_lds(
                (const __attribute__((address_space(1))) void*)(Ag + k0 + rowskip),
                (__attribute__((address_space(3))) void*)&As[2048 + wave * 512], 16, 0, 0);
            #pragma unroll
            for (int i = 0; i < 4; ++i)
                __builtin_amdgcn_global_load_lds(
                    (const __attribute__((address_space(1))) void*)(Bg + k0 + i * rowskip),
                    (__attribute__((address_space(3))) void*)&Bs[i * 2048 + wave * 512],
                    16, 0, 0);
            __syncthreads();
            #pragma unroll
            for (int kb = 0; kb < 64; kb += 32){
                const int sw = (((kb >> 3) + lq) ^ (lm & 7)) << 3;
                bf16x8 a0 = *(const bf16x8*)&As[(wm + lm) * 64 + sw];
                bf16x8 a1 = *(const bf16x8*)&As[(wm + 16 + lm) * 64 + sw];
                bf16x8 b0 = *(const bf16x8*)&Bs[(wn + lm) * 64 + sw];
                bf16x8 b1 = *(const bf16x8*)&Bs[(wn + 16 + lm) * 64 + sw];
                bf16x8 b2 = *(const bf16x8*)&Bs[(wn + 32 + lm) * 64 + sw];
                bf16x8 b3 = *(const bf16x8*)&Bs[(wn + 48 + lm) * 64 + sw];
                acc[0][0] = __builtin_amdgcn_mfma_f32_16x16x32_bf16(a0, b0, acc[0][0], 0, 0, 0);
                acc[0][1] = __builtin_amdgcn_mfma_f32_16x16x32_bf16(a0, b1, acc[0][1], 0, 0, 0);
                acc[0][2] = __builtin_amdgcn_mfma_f32_16x16x32_bf16(a0, b2, acc[0][2], 0, 0, 0);
                acc[0][3] = __builtin_amdgcn_mfma_f32_16x16x32_bf16(a0, b3, acc[0][3], 0, 0, 0);
                acc[1][0] = __builtin_amdgcn_mfma_f32_16x16x32_bf16(a1, b0, acc[1][0], 0, 0, 0);
                acc[1][1] = __builtin_amdgcn_mfma_f32_16x16x32_bf16(a1, b1, acc[1][1], 0, 0, 0);
                acc[1][2] = __builtin_amdgcn_mfma_f32_16x16x32_bf16(a1, b2, acc[1][2], 0, 0, 0);
                acc[1][3] = __builtin_amdgcn_mfma_f32_16x16x32_bf16(a1, b3, acc[1][3], 0, 0, 0);
            }
            __syncthreads();
        }
        #pragma unroll
        for (int mi = 0; mi < 2; ++mi)
          #pragma unroll
          for (int ni = 0; ni < 4; ++ni)
            #pragma unroll
            for (int r = 0; r < 4; ++r){
                int row = bm + wm + mi * 16 + lq * 4 + r;
                int col = bn + wn + ni * 16 + lm;
                out2[(size_t)row * 512 + col] = (__bf16)acc[mi][ni][r];
            }
    }
    fill_slice(smf, S5, C5, bid, 2048);
}

// ---------------- k6: ln2; ALL blocks fill C6 share ----------------
__global__ __launch_bounds__(256) void k6_ln2(const __bf16* __restrict__ X,
        const __bf16* __restrict__ o2, const float* __restrict__ bfrow,
        const float* __restrict__ b2b, const float* __restrict__ g2,
        const float* __restrict__ b2, const float* __restrict__ keyval,
        float* __restrict__ out3, f32x4* __restrict__ smf){
    __shared__ float sh[8];
    const int bid = blockIdx.x, t = threadIdx.x;
    if (bid < 8192){
        const int b = bid >> 11;
        const size_t base = (size_t)bid * 512;
        union { unsigned u; __bf16 h[2]; } xv, yv;
        xv.u = *(const unsigned*)(X + base + 2 * t);
        yv.u = *(const unsigned*)(o2 + base + 2 * t);
        float f0 = bfrow[2 * t] + b2b[2 * t], f1 = bfrow[2 * t + 1] + b2b[2 * t + 1];
        float v0 = (float)xv.h[0] + (float)yv.h[0] + f0;
        float v1 = (float)xv.h[1] + (float)yv.h[1] + f1;
        float s = v0 + v1, ss = v0 * v0 + v1 * v1;
        for (int off = 32; off; off >>= 1){ s += __shfl_down(s, off); ss += __shfl_down(ss, off); }
        int wv = t >> 6, ln = t & 63;
        if (ln == 0){ sh[wv] = s; sh[4 + wv] = ss; }
        __syncthreads();
        if (t == 0){
            float S  = sh[0] + sh[1] + sh[2] + sh[3];
            float SS = sh[4] + sh[5] + sh[6] + sh[7];
            float m = S * (1.0f / 512.0f);
            float var = SS * (1.0f / 512.0f) - m * m;
            sh[0] = m; sh[1] = rsqrtf(var + 1e-5f);
        }
        __syncthreads();
        float m = sh[0], r = sh[1];
        float2 gv = *(const float2*)(g2 + 2 * t);
        float2 bv = *(const float2*)(b2 + 2 * t);
        float2 kv = *(const float2*)(keyval + (size_t)b * 512 + 2 * t);
        float y0 = (v0 - m) * r * gv.x + bv.x + kv.x;
        float y1 = (v1 - m) * r * gv.y + bv.y + kv.y;
        *(float2*)(out3 + base + 2 * t) = make_float2(y0, y1);
    }
    fill_slice(smf, S6, C6, bid, 8704);
}

// ---------------- launch ----------------
extern "C" void kernel_launch(void* const* d_in, const int* in_sizes, int n_in,
                              void* d_out, int out_size, void* d_ws, size_t ws_size,
                              hipStream_t stream){
    const float* query  = (const float*)d_in[0];
    const float* keyval = (const float*)d_in[1];
    // d_in[2] Wq, d_in[3] bq: provably unused (softmax is uniform regardless of Q)
    const float* Wkv = (const float*)d_in[4];
    const float* bkv = (const float*)d_in[5];
    const float* Wff = (const float*)d_in[6];
    const float* bff = (const float*)d_in[7];
    const float* g1  = (const float*)d_in[8];
    const float* b1  = (const float*)d_in[9];
    const float* W2a = (const float*)d_in[10];
    const float* b2a = (const float*)d_in[11];
    const float* W2b = (const float*)d_in[12];
    const float* b2b = (const float*)d_in[13];
    const float* g2  = (const float*)d_in[14];
    const float* b2  = (const float*)d_in[15];

    float* out3 = (float*)d_out;
    f32x4* smf  = (f32x4*)(out3 + OUT3_N);

    // scratch (~24 MB): prefer d_ws; fall back to the sm region (filled last)
    char* base = (ws_size >= (64ull << 20)) ? (char*)d_ws : (char*)smf;
    float*  t_Wf   = (float*)base;                      // [576][512] fp32 (row 512 = b2a@W2b)
    float*  t_V    = t_Wf + 294912;                     // [4][1200]
    float*  t_oc   = t_V + 4800;                        // [4][512]
    __bf16* t_A1   = (__bf16*)(t_oc + 2048);            // [576][2048]
    __bf16* t_W2bT = t_A1 + 1179648;                    // [512][2048]
    __bf16* t_WfT  = t_W2bT + 1048576;                  // [512][512]
    __bf16* t_X    = t_WfT + 262144;                    // [8192][512]
    __bf16* t_out2 = t_X + 4194304;                     // [8192][512] bf16

    // zero split-K accumulators (Wf, V, oc contiguous = 301,760 floats)
    (void)hipMemsetAsync(t_Wf, 0, 301760 * sizeof(float), stream);
    k1_prep_kv<<<2848, 256, 0, stream>>>(W2a, b2a, t_A1, W2b, t_W2bT,
                                         keyval, Wkv, bkv, t_V, smf);
    k3_fold_oc<<<2048, 256, 0, stream>>>(t_A1, t_W2bT, t_Wf, t_V, Wff, bff, t_oc, smf);
    k4_ln1_tcast<<<8960, 256, 0, stream>>>(query, t_oc, g1, b1, t_X, t_Wf, t_WfT, smf);
    k5_gemm<<<2048, 256, 0, stream>>>(t_X, t_WfT, t_out2, smf);
    // bfold row = row 512 of Wf (starts at 512*512)
    k6_ln2<<<8704, 256, 0, stream>>>(t_X, t_out2, t_Wf + 262144, b2b, g2, b2,
                                     keyval, out3, smf);
}

// Round 5
// 484.802 us; speedup vs baseline: 1.1138x; 1.0007x over previous
//
#include <hip/hip_runtime.h>
#include <hip/hip_bf16.h>

// Problem constants (B=4, L=2048, D=512, M=1200, H=6)
// KEY INSIGHT: keyval is broadcast over L -> K rows identical -> softmax == 1/L exactly,
// mha == V[b] (per-batch constant), and leaky(slope=1) is identity so W2a@W2b folds.
// R13 = R12 anchor (485us) + two local edits:
//   (1) k5 fuses the X residual into its epilogue: out2' = bf16(acc + X). k6 no longer
//       reads X (saves 8.4MB read + adds in the ln2 kernel).
//   (2) k5 tiles 64x128 -> 128x128 (256 work blocks, 32KB LDS, acc[4][4]/wave): halves
//       LDS staging traffic, 2x MFMA per barrier drain, same 8 K-steps.
// Everything else (memset, split-K atomics, grids, fill slices) is R12-identical.

typedef __bf16 bf16x8 __attribute__((ext_vector_type(8)));
typedef float f32x4 __attribute__((ext_vector_type(4)));

constexpr size_t OUT3_N = 4ull * 2048 * 512;            // 4,194,304
constexpr size_t SM_N4  = (4ull * 6 * 2048 * 2048) / 4; // 25,165,824 f32x4
constexpr float  SMV    = 1.0f / 2048.0f;

// fill slice schedule (f32x4 units) — disjoint, covers SM exactly
constexpr size_t S1 = 0,        C1 = 5375000;
constexpr size_t S3 = 5375000,  C3 = 5687500;
constexpr size_t S4 = 11062500, C4 = 4750000;
constexpr size_t S5 = 15812500, C5 = 5187500;
constexpr size_t S6 = 21000000, C6 = 4165824;
static_assert(S6 + C6 == SM_N4, "fill slices must cover sm");

__device__ __forceinline__ void fill_slice(f32x4* __restrict__ p, size_t base, size_t cnt,
                                           int fb, int nfb){
    const f32x4 v = { SMV, SMV, SMV, SMV };
    const size_t stride = (size_t)nfb * 256;
    for (size_t j = (size_t)fb * 256 + threadIdx.x; j < cnt; j += stride)
        __builtin_nontemporal_store(v, p + base + j);
}

// ---------------- bf16 MFMA GEMM tile: C[64x64 at bm,bn] (+)= A[M,K] @ BT[N,K]^T over [k0beg,k0end)
// BK=64, 4 waves 2x2, global_load_lds width16, XOR-swizzled LDS (16B chunks: c8' = c8 ^ (r&7))
// MODE: 1 = atomicAdd fp32 (split-K), 2 = store bf16
template<int MODE, typename OutT>
__device__ void gemm_tile(const __bf16* __restrict__ A, const __bf16* __restrict__ BT,
                          OutT* __restrict__ C, int Ndim, int Kdim,
                          int bm, int bn, int k0beg, int k0end){
    __shared__ __bf16 As[64 * 64];
    __shared__ __bf16 Bs[64 * 64];
    const int tid = threadIdx.x, wave = tid >> 6, lane = tid & 63;
    const int r_st = wave * 8 + (lane >> 3);
    const int c8g  = (lane & 7) ^ (r_st & 7);
    const __bf16* Ag = A  + (size_t)(bm + r_st) * Kdim + c8g * 8;
    const __bf16* Bg = BT + (size_t)(bn + r_st) * Kdim + c8g * 8;
    const size_t rowskip = (size_t)32 * Kdim;
    const int wm = (wave >> 1) * 32, wn = (wave & 1) * 32;
    const int lm = lane & 15, lq = lane >> 4;
    f32x4 acc[2][2] = {};
    for (int k0 = k0beg; k0 < k0end; k0 += 64){
        __builtin_amdgcn_global_load_lds(
            (const __attribute__((address_space(1))) void*)(Ag + k0),
            (__attribute__((address_space(3))) void*)&As[wave * 512], 16, 0, 0);
        __builtin_amdgcn_global_load_lds(
            (const __attribute__((address_space(1))) void*)(Ag + k0 + rowskip),
            (__attribute__((address_space(3))) void*)&As[2048 + wave * 512], 16, 0, 0);
        __builtin_amdgcn_global_load_lds(
            (const __attribute__((address_space(1))) void*)(Bg + k0),
            (__attribute__((address_space(3))) void*)&Bs[wave * 512], 16, 0, 0);
        __builtin_amdgcn_global_load_lds(
            (const __attribute__((address_space(1))) void*)(Bg + k0 + rowskip),
            (__attribute__((address_space(3))) void*)&Bs[2048 + wave * 512], 16, 0, 0);
        __syncthreads();
        #pragma unroll
        for (int kb = 0; kb < 64; kb += 32){
            const int sw = (((kb >> 3) + lq) ^ (lm & 7)) << 3;
            bf16x8 a0 = *(const bf16x8*)&As[(wm + lm) * 64 + sw];
            bf16x8 a1 = *(const bf16x8*)&As[(wm + 16 + lm) * 64 + sw];
            bf16x8 b0 = *(const bf16x8*)&Bs[(wn + lm) * 64 + sw];
            bf16x8 b1 = *(const bf16x8*)&Bs[(wn + 16 + lm) * 64 + sw];
            acc[0][0] = __builtin_amdgcn_mfma_f32_16x16x32_bf16(a0, b0, acc[0][0], 0, 0, 0);
            acc[0][1] = __builtin_amdgcn_mfma_f32_16x16x32_bf16(a0, b1, acc[0][1], 0, 0, 0);
            acc[1][0] = __builtin_amdgcn_mfma_f32_16x16x32_bf16(a1, b0, acc[1][0], 0, 0, 0);
            acc[1][1] = __builtin_amdgcn_mfma_f32_16x16x32_bf16(a1, b1, acc[1][1], 0, 0, 0);
        }
        __syncthreads();
    }
    #pragma unroll
    for (int mi = 0; mi < 2; ++mi)
      #pragma unroll
      for (int ni = 0; ni < 2; ++ni)
        #pragma unroll
        for (int r = 0; r < 4; ++r){
            int row = bm + wm + mi * 16 + lq * 4 + r;   // C/D: row=(lane>>4)*4+reg
            int col = bn + wn + ni * 16 + lm;           //      col=lane&15
            if (MODE == 1) atomicAdd((float*)&C[(size_t)row * Ndim + col], acc[mi][ni][r]);
            else           C[(size_t)row * Ndim + col] = (OutT)acc[mi][ni][r];
        }
}

// ---------------- k1: prep + kv split-K; ALL blocks then fill their C1 share ----------------
__global__ __launch_bounds__(256) void k1_prep_kv(const float* __restrict__ W2a,
        const float* __restrict__ b2a, __bf16* __restrict__ A1,
        const float* __restrict__ W2b, __bf16* __restrict__ W2bT,
        const float* __restrict__ keyval, const float* __restrict__ Wkv,
        const float* __restrict__ bkv, float* __restrict__ V, f32x4* __restrict__ smf){
    __shared__ float sh[32 * 33];
    const int bid = blockIdx.x, tid = threadIdx.x;
    if (bid < 1152){
        int r = bid >> 1;
        int c = (bid & 1) * 1024 + tid * 4;
        float4 v;
        if (r < 512)       v = *(const float4*)(W2a + (size_t)r * 2048 + c);
        else if (r == 512) v = *(const float4*)(b2a + c);
        else               v = make_float4(0.f, 0.f, 0.f, 0.f);
        union { __bf16 h[4]; ushort4 u; } pk;
        pk.h[0] = (__bf16)v.x; pk.h[1] = (__bf16)v.y;
        pk.h[2] = (__bf16)v.z; pk.h[3] = (__bf16)v.w;
        *(ushort4*)(A1 + (size_t)r * 2048 + c) = pk.u;
    } else if (bid < 2176){
        int t = bid - 1152;                    // 1024 tiles over W2b [2048][512]
        int c0 = (t & 15) * 32, r0 = (t >> 4) * 32;
        int tx = tid & 31, ty = tid >> 5;
        for (int i = ty; i < 32; i += 8)
            sh[i * 33 + tx] = W2b[(size_t)(r0 + i) * 512 + c0 + tx];
        __syncthreads();
        for (int i = ty; i < 32; i += 8)
            W2bT[(size_t)(c0 + i) * 2048 + r0 + tx] = (__bf16)sh[tx * 33 + i];
    } else if (bid < 2336){
        int i = bid - 2176;                    // 160: b(4) x mc(5) x kc(8)
        int b = i & 3, mc = (i >> 2) % 5, kc = i / 20;
        int m = mc * 256 + tid;
        if (m < 1200){
            float acc = (kc == 0) ? bkv[1200 + m] : 0.f;
            const float* kvb = keyval + (size_t)b * 512;
            int d0 = kc * 64;
            #pragma unroll 8
            for (int d = d0; d < d0 + 64; ++d)
                acc += kvb[d] * Wkv[(size_t)d * 2400 + 1200 + m];
            atomicAdd(&V[b * 1200 + m], acc);
        }
    }
    fill_slice(smf, S1, C1, bid, 2848);
}

// ---------------- k3: fold GEMM split-K + oc GEMV; ALL blocks fill C3 share ----------------
__global__ __launch_bounds__(256) void k3_fold_oc(const __bf16* __restrict__ A1,
        const __bf16* __restrict__ W2bT, float* __restrict__ Wf,
        const float* __restrict__ V, const float* __restrict__ Wff,
        const float* __restrict__ bff, float* __restrict__ oc, f32x4* __restrict__ smf){
    const int bid = blockIdx.x, tid = threadIdx.x;
    if (bid < 288){                            // tile(9x8) x kc(4) over [576x512], K=2048
        int tile = bid % 72, kc = bid / 72;
        gemm_tile<1>(A1, W2bT, Wf, 512, 2048, (tile % 9) * 64, (tile / 9) * 64,
                     kc * 512, (kc + 1) * 512);
    } else if (bid < 384){                     // oc: b(4) x jc(2) x kc(12), K=1200
        int i = bid - 288;
        int b = i & 3, jc = (i >> 2) & 1, kc = i >> 3;
        int j = jc * 256 + tid;
        float acc = (kc == 0) ? bff[j] : 0.f;
        const float* vb = V + b * 1200;
        int m0 = kc * 100;
        #pragma unroll 5
        for (int m = m0; m < m0 + 100; ++m)
            acc += vb[m] * Wff[(size_t)m * 512 + j];
        atomicAdd(&oc[b * 512 + j], acc);
    }
    fill_slice(smf, S3, C3, bid, 2048);
}

// ---------------- k4: ln1 + tcast Wf->WfT; ALL blocks fill C4 share ----------------
__global__ __launch_bounds__(256) void k4_ln1_tcast(const float* __restrict__ q,
        const float* __restrict__ oc, const float* __restrict__ g1,
        const float* __restrict__ b1, __bf16* __restrict__ Xb,
        const float* __restrict__ Wf, __bf16* __restrict__ WfT, f32x4* __restrict__ smf){
    __shared__ float sh[32 * 33];
    const int bid = blockIdx.x, t = threadIdx.x;
    if (bid < 8192){
        const int b = bid >> 11;
        const size_t base = (size_t)bid * 512;
        float2 qv = *(const float2*)(q + base + 2 * t);
        float2 ov = *(const float2*)(oc + (size_t)b * 512 + 2 * t);
        float v0 = qv.x + ov.x, v1 = qv.y + ov.y;
        float s = v0 + v1, ss = v0 * v0 + v1 * v1;
        for (int off = 32; off; off >>= 1){ s += __shfl_down(s, off); ss += __shfl_down(ss, off); }
        int wv = t >> 6, ln = t & 63;
        if (ln == 0){ sh[wv] = s; sh[4 + wv] = ss; }
        __syncthreads();
        if (t == 0){
            float S  = sh[0] + sh[1] + sh[2] + sh[3];
            float SS = sh[4] + sh[5] + sh[6] + sh[7];
            float m = S * (1.0f / 512.0f);
            float var = SS * (1.0f / 512.0f) - m * m;
            sh[0] = m; sh[1] = rsqrtf(var + 1e-5f);
        }
        __syncthreads();
        float m = sh[0], r = sh[1];
        float2 gv = *(const float2*)(g1 + 2 * t);
        float2 bv = *(const float2*)(b1 + 2 * t);
        union { __bf16 h[2]; unsigned u; } pk;
        pk.h[0] = (__bf16)((v0 - m) * r * gv.x + bv.x);
        pk.h[1] = (__bf16)((v1 - m) * r * gv.y + bv.y);
        *(unsigned*)(Xb + base + 2 * t) = pk.u;
    } else if (bid < 8448){
        int tt = bid - 8192;                   // 256 tiles over Wf [512][512]
        int c0 = (tt & 15) * 32, r0 = (tt >> 4) * 32;
        int tx = t & 31, ty = t >> 5;
        for (int i = ty; i < 32; i += 8)
            sh[i * 33 + tx] = Wf[(size_t)(r0 + i) * 512 + c0 + tx];
        __syncthreads();
        for (int i = ty; i < 32; i += 8)
            WfT[(size_t)(c0 + i) * 512 + r0 + tx] = (__bf16)sh[tx * 33 + i];
    }
    fill_slice(smf, S4, C4, bid, 8960);
}

// ---------------- k5: main GEMM (out2' = X @ Wfold + X, bf16 out), 128x128 tiles ------
// 256 work blocks (64 m-tiles x 4 n-tiles), 32KB LDS, acc[4][4] per wave.
// Epilogue adds the X residual so k6 never reads X.
__global__ __launch_bounds__(256) void k5_gemm(const __bf16* __restrict__ X,
        const __bf16* __restrict__ WfT, __bf16* __restrict__ out2, f32x4* __restrict__ smf){
    const int bid = blockIdx.x;
    if (bid < 256){
        __shared__ __bf16 As[128 * 64];        // 16 KB
        __shared__ __bf16 Bs[128 * 64];        // 16 KB
        const int bm = (bid >> 2) * 128, bn = (bid & 3) * 128;
        const int tid = threadIdx.x, wave = tid >> 6, lane = tid & 63;
        const int r_st = wave * 8 + (lane >> 3);
        const int c8g  = (lane & 7) ^ (r_st & 7);
        const __bf16* Ag = X   + (size_t)(bm + r_st) * 512 + c8g * 8;
        const __bf16* Bg = WfT + (size_t)(bn + r_st) * 512 + c8g * 8;
        const size_t rowskip = (size_t)32 * 512;
        const int wm = (wave >> 1) * 64, wn = (wave & 1) * 64;
        const int lm = lane & 15, lq = lane >> 4;
        f32x4 acc[4][4] = {};
        for (int k0 = 0; k0 < 512; k0 += 64){
            #pragma unroll
            for (int j = 0; j < 4; ++j){
                __builtin_amdgcn_global_load_lds(
                    (const __attribute__((address_space(1))) void*)(Ag + k0 + j * rowskip),
                    (__attribute__((address_space(3))) void*)&As[j * 2048 + wave * 512],
                    16, 0, 0);
                __builtin_amdgcn_global_load_lds(
                    (const __attribute__((address_space(1))) void*)(Bg + k0 + j * rowskip),
                    (__attribute__((address_space(3))) void*)&Bs[j * 2048 + wave * 512],
                    16, 0, 0);
            }
            __syncthreads();
            #pragma unroll
            for (int kb = 0; kb < 64; kb += 32){
                const int sw = (((kb >> 3) + lq) ^ (lm & 7)) << 3;
                bf16x8 a[4], b[4];
                #pragma unroll
                for (int j = 0; j < 4; ++j){
                    a[j] = *(const bf16x8*)&As[(wm + j * 16 + lm) * 64 + sw];
                    b[j] = *(const bf16x8*)&Bs[(wn + j * 16 + lm) * 64 + sw];
                }
                #pragma unroll
                for (int mi = 0; mi < 4; ++mi)
                    #pragma unroll
                    for (int ni = 0; ni < 4; ++ni)
                        acc[mi][ni] = __builtin_amdgcn_mfma_f32_16x16x32_bf16(
                            a[mi], b[ni], acc[mi][ni], 0, 0, 0);
            }
            __syncthreads();
        }
        #pragma unroll
        for (int mi = 0; mi < 4; ++mi)
          #pragma unroll
          for (int ni = 0; ni < 4; ++ni)
            #pragma unroll
            for (int r = 0; r < 4; ++r){
                int row = bm + wm + mi * 16 + lq * 4 + r;
                int col = bn + wn + ni * 16 + lm;
                float xv = (float)X[(size_t)row * 512 + col];
                out2[(size_t)row * 512 + col] = (__bf16)(acc[mi][ni][r] + xv);
            }
    }
    fill_slice(smf, S5, C5, bid, 2048);
}

// ---------------- k6: ln2 (out2' already includes X); ALL blocks fill C6 share ----------------
__global__ __launch_bounds__(256) void k6_ln2(const __bf16* __restrict__ o2,
        const float* __restrict__ bfrow, const float* __restrict__ b2b,
        const float* __restrict__ g2, const float* __restrict__ b2,
        const float* __restrict__ keyval, float* __restrict__ out3,
        f32x4* __restrict__ smf){
    __shared__ float sh[8];
    const int bid = blockIdx.x, t = threadIdx.x;
    if (bid < 8192){
        const int b = bid >> 11;
        const size_t base = (size_t)bid * 512;
        union { unsigned u; __bf16 h[2]; } yv;
        yv.u = *(const unsigned*)(o2 + base + 2 * t);
        float f0 = bfrow[2 * t] + b2b[2 * t], f1 = bfrow[2 * t + 1] + b2b[2 * t + 1];
        float v0 = (float)yv.h[0] + f0;
        float v1 = (float)yv.h[1] + f1;
        float s = v0 + v1, ss = v0 * v0 + v1 * v1;
        for (int off = 32; off; off >>= 1){ s += __shfl_down(s, off); ss += __shfl_down(ss, off); }
        int wv = t >> 6, ln = t & 63;
        if (ln == 0){ sh[wv] = s; sh[4 + wv] = ss; }
        __syncthreads();
        if (t == 0){
            float S  = sh[0] + sh[1] + sh[2] + sh[3];
            float SS = sh[4] + sh[5] + sh[6] + sh[7];
            float m = S * (1.0f / 512.0f);
            float var = SS * (1.0f / 512.0f) - m * m;
            sh[0] = m; sh[1] = rsqrtf(var + 1e-5f);
        }
        __syncthreads();
        float m = sh[0], r = sh[1];
        float2 gv = *(const float2*)(g2 + 2 * t);
        float2 bv = *(const float2*)(b2 + 2 * t);
        float2 kv = *(const float2*)(keyval + (size_t)b * 512 + 2 * t);
        float y0 = (v0 - m) * r * gv.x + bv.x + kv.x;
        float y1 = (v1 - m) * r * gv.y + bv.y + kv.y;
        *(float2*)(out3 + base + 2 * t) = make_float2(y0, y1);
    }
    fill_slice(smf, S6, C6, bid, 8704);
}

// ---------------- launch ----------------
extern "C" void kernel_launch(void* const* d_in, const int* in_sizes, int n_in,
                              void* d_out, int out_size, void* d_ws, size_t ws_size,
                              hipStream_t stream){
    const float* query  = (const float*)d_in[0];
    const float* keyval = (const float*)d_in[1];
    // d_in[2] Wq, d_in[3] bq: provably unused (softmax is uniform regardless of Q)
    const float* Wkv = (const float*)d_in[4];
    const float* bkv = (const float*)d_in[5];
    const float* Wff = (const float*)d_in[6];
    const float* bff = (const float*)d_in[7];
    const float* g1  = (const float*)d_in[8];
    const float* b1  = (const float*)d_in[9];
    const float* W2a = (const float*)d_in[10];
    const float* b2a = (const float*)d_in[11];
    const float* W2b = (const float*)d_in[12];
    const float* b2b = (const float*)d_in[13];
    const float* g2  = (const float*)d_in[14];
    const float* b2  = (const float*)d_in[15];

    float* out3 = (float*)d_out;
    f32x4* smf  = (f32x4*)(out3 + OUT3_N);

    // scratch (~24 MB): prefer d_ws; fall back to the sm region (filled last)
    char* base = (ws_size >= (64ull << 20)) ? (char*)d_ws : (char*)smf;
    float*  t_Wf   = (float*)base;                      // [576][512] fp32 (row 512 = b2a@W2b)
    float*  t_V    = t_Wf + 294912;                     // [4][1200]
    float*  t_oc   = t_V + 4800;                        // [4][512]
    __bf16* t_A1   = (__bf16*)(t_oc + 2048);            // [576][2048]
    __bf16* t_W2bT = t_A1 + 1179648;                    // [512][2048]
    __bf16* t_WfT  = t_W2bT + 1048576;                  // [512][512]
    __bf16* t_X    = t_WfT + 262144;                    // [8192][512]
    __bf16* t_out2 = t_X + 4194304;                     // [8192][512] bf16 (= out2 + X)

    // zero split-K accumulators (Wf, V, oc contiguous = 301,760 floats)
    (void)hipMemsetAsync(t_Wf, 0, 301760 * sizeof(float), stream);
    k1_prep_kv<<<2848, 256, 0, stream>>>(W2a, b2a, t_A1, W2b, t_W2bT,
                                         keyval, Wkv, bkv, t_V, smf);
    k3_fold_oc<<<2048, 256, 0, stream>>>(t_A1, t_W2bT, t_Wf, t_V, Wff, bff, t_oc, smf);
    k4_ln1_tcast<<<8960, 256, 0, stream>>>(query, t_oc, g1, b1, t_X, t_Wf, t_WfT, smf);
    k5_gemm<<<2048, 256, 0, stream>>>(t_X, t_WfT, t_out2, smf);
    // bfold row = row 512 of Wf (starts at 512*512)
    k6_ln2<<<8704, 256, 0, stream>>>(t_out2, t_Wf + 262144, b2b, g2, b2,
                                     keyval, out3, smf);
}